// Round 6
// baseline (79.200 us; speedup 1.0000x reference)
//
#include <hip/hip_runtime.h>

// m_ij = MLP([dist, dist^-3]) is a scalar function of s = |r|^2 + eps^2 only.
// Kernel 1 tabulates m(s) at float-bit sample points (6 mantissa bits x 22
// octaves, s in [2^-14, 2^8]) and zeroes d_out. Kernel 2 does symmetric
// all-pairs acc[i] = sum_j m(s_ij)*(p_j - p_i)  (j==i term is exactly 0).
// m evaluated from an LDS table of per-interval (slope,intercept) packed as
// 2xbf16 in one dword: one ds_read_b32 gather + unpack + fma per pair.
// p_j is wave-uniform -> scalar loads.

#define EPS2      1.0e-4f
#define TAB_BITS  6
#define TAB_SHIFT (23 - TAB_BITS)            // 17
#define TAB_EMIN  113                        // biased exponent of 2^-14
#define TAB_BASE  (TAB_EMIN << TAB_BITS)     // 7232
#define TAB_OCT   22                         // 2^-14 .. 2^8
#define TAB_N     (TAB_OCT << TAB_BITS)      // 1408 intervals

#define NPART  2048
#define BLOCK  512
#define CHUNK  512                           // i-particles per block
#define NSPLIT 32                            // j-range splits (256 blocks = 1/CU)
#define JPT    (NPART / NSPLIT)              // 64 j per block's range

__device__ __forceinline__ unsigned bf16_hi(float x) {
    // round-to-nearest bf16, return bits in the HIGH half (valid f32 when low=0)
    return (__float_as_uint(x) + 0x8000u) & 0xFFFF0000u;
}

// ---- table build: 64 threads/entry, one output channel per lane ----------
// W2[k*64 + lane] is a coalesced 256B/wave load; W1/b1 are wave-uniform.
__global__ void build_table(const float* __restrict__ W1, const float* __restrict__ b1,
                            const float* __restrict__ W2, const float* __restrict__ b2,
                            const float* __restrict__ W3, const float* __restrict__ b3,
                            float* __restrict__ tab, float* __restrict__ out, int out_n) {
    const int t = blockIdx.x * blockDim.x + threadIdx.x;

    if (t < out_n) out[t] = 0.0f;            // harness poisons d_out to 0xAA

    const int entry = t >> 6;
    const int o     = t & 63;                // output channel == lane
    if (entry > TAB_N) return;

    const unsigned u = (unsigned)(entry + TAB_BASE) << TAB_SHIFT;
    const float s = __uint_as_float(u);      // exact sample point
    const float d = sqrtf(s);
    const float idc = 1.0f / (s * d);

    float acc = b2[o];
#pragma unroll
    for (int k = 0; k < 64; ++k) {
        float hv = fmaf(d, W1[k], fmaf(idc, W1[64 + k], b1[k]));
        hv = hv > 0.0f ? hv : 0.0f;
        acc = fmaf(hv, W2[k * 64 + o], acc);
    }
    float part = (acc > 0.0f ? acc : 0.0f) * W3[o];

    part += __shfl_down(part, 32, 64);
    part += __shfl_down(part, 16, 64);
    part += __shfl_down(part, 8, 64);
    part += __shfl_down(part, 4, 64);
    part += __shfl_down(part, 2, 64);
    part += __shfl_down(part, 1, 64);
    if (o == 0) tab[entry] = part + b3[0];
}

// ---------------- all-pairs force accumulation -----------------------------
__global__ __launch_bounds__(BLOCK, 4)
void forces(const float* __restrict__ pos, const float* __restrict__ tab,
            float* __restrict__ out) {
    __shared__ unsigned tabs[TAB_N];         // packed bf16 (slope, intercept): 5632 B

    const int tid = threadIdx.x;

    // stage table as packed bf16 (a,b): m(s) = a*s + b on each interval.
    // Interval width is an exact power of 2 -> reciprocal via exponent bits.
    // Intercept is computed against the ROUNDED slope so the interval start
    // stays anchored; each bf16 rounding adds <=2^-9 relative error.
    for (int k = tid; k < TAB_N; k += BLOCK) {
        float t0 = tab[k], t1 = tab[k + 1];
        float s0 = __uint_as_float((unsigned)(k + TAB_BASE) << TAB_SHIFT);
        float rcpw = __uint_as_float((unsigned)(147 - (k >> TAB_BITS)) << 23);
        unsigned abits = bf16_hi((t1 - t0) * rcpw);
        float ar = __uint_as_float(abits);
        unsigned bbits = bf16_hi(fmaf(-ar, s0, t0));
        tabs[k] = bbits | (abits >> 16);
    }
    __syncthreads();

    const int split = blockIdx.x;
    const int chunk = blockIdx.y;
    const int b     = blockIdx.z;

    const float* posb = pos + (size_t)b * NPART * 3;
    const int i = chunk * CHUNK + tid;
    const float pix = posb[i * 3 + 0];
    const float piy = posb[i * 3 + 1];
    const float piz = posb[i * 3 + 2];

    float ax = 0.0f, ay = 0.0f, az = 0.0f;
    const float* pj = posb + split * JPT * 3;    // wave-uniform -> s_load

#pragma unroll 8
    for (int jj = 0; jj < JPT; ++jj) {
        float dx = pj[jj * 3 + 0] - pix;
        float dy = pj[jj * 3 + 1] - piy;
        float dz = pj[jj * 3 + 2] - piz;
        float s = fmaf(dx, dx, fmaf(dy, dy, fmaf(dz, dz, EPS2)));
        // s >= EPS2 = 1e-4 > 2^-14 so no underflow; unsigned min clamps high.
        unsigned idx = (__float_as_uint(s) >> TAB_SHIFT) - TAB_BASE;
        idx = idx > TAB_N - 1u ? TAB_N - 1u : idx;
        unsigned p = tabs[idx];                  // one ds_read_b32 gather
        float a  = __uint_as_float(p << 16);
        float bb = __uint_as_float(p & 0xFFFF0000u);
        float m = fmaf(s, a, bb);
        ax = fmaf(m, dx, ax);
        ay = fmaf(m, dy, ay);
        az = fmaf(m, dz, az);
    }

    float* o = out + ((size_t)b * NPART + i) * 3;
    atomicAdd(o + 0, ax);
    atomicAdd(o + 1, ay);
    atomicAdd(o + 2, az);
}

extern "C" void kernel_launch(void* const* d_in, const int* in_sizes, int n_in,
                              void* d_out, int out_size, void* d_ws, size_t ws_size,
                              hipStream_t stream) {
    const float* pos = (const float*)d_in[0];
    const float* W1  = (const float*)d_in[1];
    const float* b1  = (const float*)d_in[2];
    const float* W2  = (const float*)d_in[3];
    const float* b2  = (const float*)d_in[4];
    const float* W3  = (const float*)d_in[5];
    const float* b3  = (const float*)d_in[6];
    float* out = (float*)d_out;
    float* tab = (float*)d_ws;               // (TAB_N+1) floats

    const int B = in_sizes[0] / (NPART * 3); // = 2

    const int build_threads = (TAB_N + 1) * 64;  // 90176 >= out_size (12288)
    build_table<<<(build_threads + 255) / 256, 256, 0, stream>>>(
        W1, b1, W2, b2, W3, b3, tab, out, out_size);

    forces<<<dim3(NSPLIT, NPART / CHUNK, B), BLOCK, 0, stream>>>(pos, tab, out);
}

// Round 7
// 78.585 us; speedup vs baseline: 1.0078x; 1.0078x over previous
//
#include <hip/hip_runtime.h>

// m_ij = MLP([dist, dist^-3]) is a scalar function of s = |r|^2 + eps^2 only.
// Kernel 1 tabulates m(s) at float-bit sample points (6 mantissa bits x 22
// octaves, s in [2^-14, 2^8]) and zeroes d_out. Kernel 2 does symmetric
// all-pairs acc[i] = sum_j m(s_ij)*(p_j - p_i)  (j==i term is exactly 0),
// evaluating m via a per-interval (slope,intercept) LDS table: one
// ds_read_b64 gather + one fma per pair. p_j is wave-uniform -> scalar loads.
// (R6's bf16-packed table was time-neutral with 4x worse absmax -> reverted.)

#define EPS2      1.0e-4f
#define TAB_BITS  6
#define TAB_SHIFT (23 - TAB_BITS)            // 17
#define TAB_EMIN  113                        // biased exponent of 2^-14
#define TAB_BASE  (TAB_EMIN << TAB_BITS)     // 7232
#define TAB_OCT   22                         // 2^-14 .. 2^8
#define TAB_N     (TAB_OCT << TAB_BITS)      // 1408 intervals

#define NPART  2048
#define BLOCK  512
#define CHUNK  512                           // i-particles per block
#define NSPLIT 32                            // j-range splits (256 blocks = 1/CU)
#define JPT    (NPART / NSPLIT)              // 64 j per block's range

// ---- table build: 64 threads/entry, one output channel per lane ----------
// W2[k*64 + lane] is a coalesced 256B/wave load; W1/b1 are wave-uniform.
__global__ void build_table(const float* __restrict__ W1, const float* __restrict__ b1,
                            const float* __restrict__ W2, const float* __restrict__ b2,
                            const float* __restrict__ W3, const float* __restrict__ b3,
                            float* __restrict__ tab, float* __restrict__ out, int out_n) {
    const int t = blockIdx.x * blockDim.x + threadIdx.x;

    if (t < out_n) out[t] = 0.0f;            // harness poisons d_out to 0xAA

    const int entry = t >> 6;
    const int o     = t & 63;                // output channel == lane
    if (entry > TAB_N) return;

    const unsigned u = (unsigned)(entry + TAB_BASE) << TAB_SHIFT;
    const float s = __uint_as_float(u);      // exact sample point
    const float d = sqrtf(s);
    const float idc = 1.0f / (s * d);

    float acc = b2[o];
#pragma unroll
    for (int k = 0; k < 64; ++k) {
        float hv = fmaf(d, W1[k], fmaf(idc, W1[64 + k], b1[k]));
        hv = hv > 0.0f ? hv : 0.0f;
        acc = fmaf(hv, W2[k * 64 + o], acc);
    }
    float part = (acc > 0.0f ? acc : 0.0f) * W3[o];

    part += __shfl_down(part, 32, 64);
    part += __shfl_down(part, 16, 64);
    part += __shfl_down(part, 8, 64);
    part += __shfl_down(part, 4, 64);
    part += __shfl_down(part, 2, 64);
    part += __shfl_down(part, 1, 64);
    if (o == 0) tab[entry] = part + b3[0];
}

// ---------------- all-pairs force accumulation -----------------------------
__global__ __launch_bounds__(BLOCK, 4)
void forces(const float* __restrict__ pos, const float* __restrict__ tab,
            float* __restrict__ out) {
    __shared__ float2 tabs[TAB_N + 1];       // (slope, intercept): 11272 B

    const int tid = threadIdx.x;

    // stage table as (a,b): m(s) = a*s + b on each interval. Interval width
    // is an exact power of 2 -> reciprocal by exponent arithmetic.
    for (int k = tid; k < TAB_N; k += BLOCK) {
        float t0 = tab[k], t1 = tab[k + 1];
        float s0 = __uint_as_float((unsigned)(k + TAB_BASE) << TAB_SHIFT);
        float rcpw = __uint_as_float((unsigned)(147 - (k >> TAB_BITS)) << 23);
        float a = (t1 - t0) * rcpw;
        tabs[k] = make_float2(a, fmaf(-a, s0, t0));
    }
    __syncthreads();

    const int split = blockIdx.x;
    const int chunk = blockIdx.y;
    const int b     = blockIdx.z;

    const float* posb = pos + (size_t)b * NPART * 3;
    const int i = chunk * CHUNK + tid;
    const float pix = posb[i * 3 + 0];
    const float piy = posb[i * 3 + 1];
    const float piz = posb[i * 3 + 2];

    float ax = 0.0f, ay = 0.0f, az = 0.0f;
    const float* pj = posb + split * JPT * 3;    // wave-uniform -> s_load

#pragma unroll 8
    for (int jj = 0; jj < JPT; ++jj) {
        float dx = pj[jj * 3 + 0] - pix;
        float dy = pj[jj * 3 + 1] - piy;
        float dz = pj[jj * 3 + 2] - piz;
        float s = fmaf(dx, dx, fmaf(dy, dy, fmaf(dz, dz, EPS2)));
        // s >= EPS2 = 1e-4 > 2^-14 so no underflow; unsigned min clamps high.
        unsigned idx = (__float_as_uint(s) >> TAB_SHIFT) - TAB_BASE;
        idx = idx > TAB_N - 1u ? TAB_N - 1u : idx;
        float2 ab = tabs[idx];                   // one ds_read_b64 gather
        float m = fmaf(s, ab.x, ab.y);
        ax = fmaf(m, dx, ax);
        ay = fmaf(m, dy, ay);
        az = fmaf(m, dz, az);
    }

    float* o = out + ((size_t)b * NPART + i) * 3;
    atomicAdd(o + 0, ax);
    atomicAdd(o + 1, ay);
    atomicAdd(o + 2, az);
}

extern "C" void kernel_launch(void* const* d_in, const int* in_sizes, int n_in,
                              void* d_out, int out_size, void* d_ws, size_t ws_size,
                              hipStream_t stream) {
    const float* pos = (const float*)d_in[0];
    const float* W1  = (const float*)d_in[1];
    const float* b1  = (const float*)d_in[2];
    const float* W2  = (const float*)d_in[3];
    const float* b2  = (const float*)d_in[4];
    const float* W3  = (const float*)d_in[5];
    const float* b3  = (const float*)d_in[6];
    float* out = (float*)d_out;
    float* tab = (float*)d_ws;               // (TAB_N+1) floats

    const int B = in_sizes[0] / (NPART * 3); // = 2

    const int build_threads = (TAB_N + 1) * 64;  // 90176 >= out_size (12288)
    build_table<<<(build_threads + 255) / 256, 256, 0, stream>>>(
        W1, b1, W2, b2, W3, b3, tab, out, out_size);

    forces<<<dim3(NSPLIT, NPART / CHUNK, B), BLOCK, 0, stream>>>(pos, tab, out);
}